// Round 2
// baseline (511.411 us; speedup 1.0000x reference)
//
#include <hip/hip_runtime.h>
#include <hip/hip_bf16.h>

// Problem constants
#define NB   4
#define SEQ  2048
#define DMODEL 1024
#define NHEAD 16
#define HDIM 64
#define MROWS (NB * SEQ)          // 8192
#define N_QKV (3 * DMODEL)        // 3072

typedef __attribute__((ext_vector_type(8))) short bf16x8;
typedef __attribute__((ext_vector_type(4))) float f32x4;

#define MFMA16(a, b, c) __builtin_amdgcn_mfma_f32_16x16x32_bf16((a), (b), (c), 0, 0, 0)

__device__ inline bf16x8 load8(const __hip_bfloat16* p) {
    union { uint2 u[2]; bf16x8 v; } t;
    t.u[0] = *(const uint2*)p;
    t.u[1] = *(const uint2*)(p + 4);
    return t.v;
}

// fp32 -> bf16 raw bits, round-to-nearest-even (matches HW conversion for finite vals)
__device__ inline ushort f2bf(float f) {
    union { float f; unsigned int u; } a;
    a.f = f;
    unsigned int r = a.u + 0x7FFFu + ((a.u >> 16) & 1u);
    return (ushort)(r >> 16);
}

// ---------------- cast fp32 -> bf16, 4 elems/thread ----------------
__global__ __launch_bounds__(256)
void cast_bf16_kernel(const float* __restrict__ in, ushort* __restrict__ out, int n) {
    int idx = (blockIdx.x * 256 + threadIdx.x) * 4;
    if (idx + 3 < n) {
        float4 v = *(const float4*)(in + idx);
        ushort4 o;
        o.x = f2bf(v.x);
        o.y = f2bf(v.y);
        o.z = f2bf(v.z);
        o.w = f2bf(v.w);
        *(ushort4*)(out + idx) = o;
    }
}

// ---------------- C[M,N] = A[M,K] * B[N,K]^T  (bf16 in, f32 acc) ----------------
// 128x128 tile, BK=32, 4 waves each own a 64x64 quadrant (4x4 MFMA 16x16x32 tiles).
template<int OUT_F32>
__global__ __launch_bounds__(256)
void gemm_bt(const __hip_bfloat16* __restrict__ A,
             const __hip_bfloat16* __restrict__ Bm,
             ushort* __restrict__ Cb,
             float* __restrict__ Cf,
             int M, int N, int K) {
    constexpr int BM = 128, BN = 128, BK = 32, LDT = 40; // +8 pad: 80B stride -> 2-way (free) banks
    __shared__ __hip_bfloat16 As[BM * LDT];
    __shared__ __hip_bfloat16 Bs[BN * LDT];

    const int tid  = threadIdx.x;
    const int lane = tid & 63;
    const int wave = tid >> 6;
    const int wr = (wave >> 1) * 64;   // wave row quadrant
    const int wc = (wave & 1) * 64;    // wave col quadrant
    const int quad = lane >> 4;
    const int l16  = lane & 15;

    const int row0 = blockIdx.y * BM;
    const int col0 = blockIdx.x * BN;

    f32x4 acc[4][4];
#pragma unroll
    for (int i = 0; i < 4; i++)
#pragma unroll
        for (int j = 0; j < 4; j++) acc[i][j] = (f32x4)0.0f;

    for (int k0 = 0; k0 < K; k0 += BK) {
        // stage A,B tiles: 512 chunks of 8 bf16 each, 256 threads x 2
#pragma unroll
        for (int i = 0; i < 2; i++) {
            int e = tid + i * 256;
            int r = e >> 2;
            int c = (e & 3) * 8;
            uint4 av = *(const uint4*)(A + (size_t)(row0 + r) * K + k0 + c);
            uint4 bv = *(const uint4*)(Bm + (size_t)(col0 + r) * K + k0 + c);
            *(uint2*)&As[r * LDT + c]     = make_uint2(av.x, av.y);
            *(uint2*)&As[r * LDT + c + 4] = make_uint2(av.z, av.w);
            *(uint2*)&Bs[r * LDT + c]     = make_uint2(bv.x, bv.y);
            *(uint2*)&Bs[r * LDT + c + 4] = make_uint2(bv.z, bv.w);
        }
        __syncthreads();

        bf16x8 af[4], bfr[4];
#pragma unroll
        for (int t = 0; t < 4; t++) {
            af[t]  = load8(&As[(wr + t * 16 + l16) * LDT + quad * 8]);
            bfr[t] = load8(&Bs[(wc + t * 16 + l16) * LDT + quad * 8]);
        }
#pragma unroll
        for (int i = 0; i < 4; i++)
#pragma unroll
            for (int j = 0; j < 4; j++)
                acc[i][j] = MFMA16(af[i], bfr[j], acc[i][j]);
        __syncthreads();
    }

    // epilogue: C/D layout col=lane&15, row=quad*4+reg
#pragma unroll
    for (int i = 0; i < 4; i++) {
#pragma unroll
        for (int r = 0; r < 4; r++) {
            size_t grow = (size_t)(row0 + wr + i * 16 + quad * 4 + r);
#pragma unroll
            for (int j = 0; j < 4; j++) {
                int gcol = col0 + wc + j * 16 + l16;
                float v = acc[i][j][r];
                if (OUT_F32) Cf[grow * N + gcol] = v;
                else         Cb[grow * N + gcol] = f2bf(v);
            }
        }
    }
}

// ---------------- flash attention, causal ----------------
// grid.x = S/64 q-tiles, grid.y = B*H. 4 waves x 16 q-rows. TK=64 key tile.
__global__ __launch_bounds__(256)
void attn_kernel(const __hip_bfloat16* __restrict__ qkv, ushort* __restrict__ O) {
    constexpr int TK = 64, LDK = 72; // 144B stride -> 2-way (free) banks
    __shared__ __hip_bfloat16 Kld[TK * LDK];
    __shared__ __hip_bfloat16 Vt[HDIM * LDK];
    __shared__ ushort Pld[4][16 * LDK];

    const int tid  = threadIdx.x;
    const int lane = tid & 63;
    const int wave = tid >> 6;
    const int quad = lane >> 4;
    const int l16  = lane & 15;

    const int qtile = blockIdx.x;          // 0..31
    const int bh    = blockIdx.y;          // 0..63
    const int b = bh >> 4, h = bh & 15;
    const size_t rowbase = (size_t)b * SEQ;
    const int q0 = qtile * 64;

    // Q fragments (A-layout: m=lane&15, k=quad*8+j), held for whole key loop
    const __hip_bfloat16* qp = qkv + (rowbase + q0 + wave * 16 + l16) * N_QKV + h * HDIM;
    bf16x8 qf0 = load8(qp + quad * 8);
    bf16x8 qf1 = load8(qp + 32 + quad * 8);

    float mr[4], lr[4];
    f32x4 oacc[4];
#pragma unroll
    for (int r = 0; r < 4; r++) { mr[r] = -1e30f; lr[r] = 0.0f; }
#pragma unroll
    for (int t = 0; t < 4; t++) oacc[t] = (f32x4)0.0f;

    const int niter = qtile + 1;
    for (int it = 0; it < niter; ++it) {
        const int k0 = it * TK;
        __syncthreads(); // previous iter's LDS reads done before restaging

        // stage K tile [64 keys][64 d] and V^T tile [64 d][64 keys]
#pragma unroll
        for (int i = 0; i < 2; i++) {
            int e = tid + i * 256;          // 512 chunks of 8
            int r = e >> 3;
            int c = (e & 7) * 8;
            const __hip_bfloat16* kp = qkv + (rowbase + k0 + r) * N_QKV + DMODEL + h * HDIM + c;
            const __hip_bfloat16* vp = qkv + (rowbase + k0 + r) * N_QKV + 2 * DMODEL + h * HDIM + c;
            uint4 kv = *(const uint4*)kp;
            *(uint2*)&Kld[r * LDK + c]     = make_uint2(kv.x, kv.y);
            *(uint2*)&Kld[r * LDK + c + 4] = make_uint2(kv.z, kv.w);
            union { uint4 u; ushort s[8]; } vv;
            vv.u = *(const uint4*)vp;
#pragma unroll
            for (int j = 0; j < 8; j++)
                ((ushort*)Vt)[(c + j) * LDK + r] = vv.s[j];
        }
        __syncthreads();

        // S = Q K^T (rows=q local, cols=key local)
        f32x4 s[4];
#pragma unroll
        for (int t = 0; t < 4; t++) {
            bf16x8 kb0 = load8(&Kld[(t * 16 + l16) * LDK + quad * 8]);
            bf16x8 kb1 = load8(&Kld[(t * 16 + l16) * LDK + 32 + quad * 8]);
            f32x4 z = (f32x4)0.0f;
            z = MFMA16(qf0, kb0, z);
            z = MFMA16(qf1, kb1, z);
            s[t] = z;
        }

        // online softmax (per C-layout row = quad*4+r; 16 lanes of a quad share a row)
        const int myq = q0 + wave * 16 + quad * 4;
        float p[4][4];
#pragma unroll
        for (int r = 0; r < 4; r++) {
            float mt = -1e30f;
#pragma unroll
            for (int t = 0; t < 4; t++) {
                float sv = s[t][r] * 0.125f;            // 1/sqrt(64)
                int key = k0 + t * 16 + l16;
                sv = (key <= myq + r) ? sv : -1e30f;    // causal mask
                p[t][r] = sv;
                mt = fmaxf(mt, sv);
            }
            mt = fmaxf(mt, __shfl_xor(mt, 1));
            mt = fmaxf(mt, __shfl_xor(mt, 2));
            mt = fmaxf(mt, __shfl_xor(mt, 4));
            mt = fmaxf(mt, __shfl_xor(mt, 8));
            float mnew  = fmaxf(mr[r], mt);
            float alpha = __expf(mr[r] - mnew);
            mr[r] = mnew;
            float rs = 0.0f;
#pragma unroll
            for (int t = 0; t < 4; t++) {
                float pv = __expf(p[t][r] - mnew);
                p[t][r] = pv;
                rs += pv;
            }
            rs += __shfl_xor(rs, 1);
            rs += __shfl_xor(rs, 2);
            rs += __shfl_xor(rs, 4);
            rs += __shfl_xor(rs, 8);
            lr[r] = lr[r] * alpha + rs;
#pragma unroll
            for (int t = 0; t < 4; t++) oacc[t][r] *= alpha;
        }

        // P: C-layout -> LDS -> A-layout (per-wave region, wave-synchronous)
#pragma unroll
        for (int t = 0; t < 4; t++)
#pragma unroll
            for (int r = 0; r < 4; r++)
                Pld[wave][(quad * 4 + r) * LDK + t * 16 + l16] = f2bf(p[t][r]);

        // O += P V
        bf16x8 pa0 = load8((const __hip_bfloat16*)&Pld[wave][l16 * LDK + quad * 8]);
        bf16x8 pa1 = load8((const __hip_bfloat16*)&Pld[wave][l16 * LDK + 32 + quad * 8]);
#pragma unroll
        for (int t = 0; t < 4; t++) {
            bf16x8 vb0 = load8(&Vt[(t * 16 + l16) * LDK + quad * 8]);
            bf16x8 vb1 = load8(&Vt[(t * 16 + l16) * LDK + 32 + quad * 8]);
            oacc[t] = MFMA16(pa0, vb0, oacc[t]);
            oacc[t] = MFMA16(pa1, vb1, oacc[t]);
        }
    }

    // normalize + store O as bf16 [B*S, D] at head offset
#pragma unroll
    for (int t = 0; t < 4; t++) {
#pragma unroll
        for (int r = 0; r < 4; r++) {
            float v = oacc[t][r] / lr[r];
            O[(rowbase + q0 + wave * 16 + quad * 4 + r) * DMODEL + h * HDIM + t * 16 + l16] =
                f2bf(v);
        }
    }
}

extern "C" void kernel_launch(void* const* d_in, const int* in_sizes, int n_in,
                              void* d_out, int out_size, void* d_ws, size_t ws_size,
                              hipStream_t stream) {
    const float* x      = (const float*)d_in[0];
    const float* w_attn = (const float*)d_in[1];
    const float* w_proj = (const float*)d_in[2];
    float* out = (float*)d_out;

    // workspace layout (bf16 elements): x | w_attn | w_proj | qkv | o
    ushort* ws   = (ushort*)d_ws;
    ushort* xb   = ws;
    ushort* wab  = xb  + (size_t)MROWS * DMODEL;
    ushort* wpb  = wab + (size_t)N_QKV * DMODEL;
    ushort* qkvb = wpb + (size_t)DMODEL * DMODEL;
    ushort* ob   = qkvb + (size_t)MROWS * N_QKV;

    const int n_x = MROWS * DMODEL;      // 8388608
    const int n_wa = N_QKV * DMODEL;     // 3145728
    const int n_wp = DMODEL * DMODEL;    // 1048576

    cast_bf16_kernel<<<n_x / 1024, 256, 0, stream>>>(x, xb, n_x);
    cast_bf16_kernel<<<n_wa / 1024, 256, 0, stream>>>(w_attn, wab, n_wa);
    cast_bf16_kernel<<<n_wp / 1024, 256, 0, stream>>>(w_proj, wpb, n_wp);

    // qkv = x @ w_attn^T   [8192,3072]
    gemm_bt<0><<<dim3(N_QKV / 128, MROWS / 128), 256, 0, stream>>>(
        (const __hip_bfloat16*)xb, (const __hip_bfloat16*)wab, qkvb, nullptr,
        MROWS, N_QKV, DMODEL);

    // flash attention -> o  [8192,1024] bf16
    attn_kernel<<<dim3(SEQ / 64, NB * NHEAD), 256, 0, stream>>>(
        (const __hip_bfloat16*)qkvb, ob);

    // out = o @ w_proj^T   [8192,1024] f32
    gemm_bt<1><<<dim3(DMODEL / 128, MROWS / 128), 256, 0, stream>>>(
        (const __hip_bfloat16*)ob, (const __hip_bfloat16*)wpb, nullptr, out,
        MROWS, DMODEL, DMODEL);
}